// Round 15
// baseline (87.626 us; speedup 1.0000x reference)
//
#include <hip/hip_runtime.h>

// ---------------------------------------------------------------------------
// out[b,o] = sum_{f,p} x0[b,f]*x[b,p]*W[o,f,p] + bias[o]
//   == GEMM C[4096,256] = A[4096,16384] * W^T,  A[b,f*128+p] = x0[b,f]*x[b,p]
// R15: 1 wave/SIMD + FULL register residency (ILP-for-TLP). Session evidence:
// every >=2 wave/SIMD config caps at 128 VGPR -> allocator demotes A-state /
// B-ring (VGPR=84 in R8/R9/R14) -> per-window refetch + exposed latency ->
// ~840 GF plateau. Here __launch_bounds__(256,1) opens the 512-reg budget:
// block = 4 waves (one per SIMD), grid 256 = 64mb x 4sk, wave = 64r x 64o x
// 4096k = 128 q-major windows. Resident: acc 64 + xa[4][4] (ALL q, zero
// A-reloads) 64 + x0v 32 + 4-deep named B-ring 64 ~= 280 regs. Window =
// 4 coalesced dwordx4 + 16 MFMA, prefetch 3 ahead (~270cyc cover > L2 ~200),
// no LDS/barriers/asm in loop. sk slice per XCD (bid&7) -> 2MB L2-resident.
// Epilogue: split-K-4 f32 atomics onto bias-pre-initialized out.
// ---------------------------------------------------------------------------

typedef _Float16 f16x8 __attribute__((ext_vector_type(8)));
typedef float    f32x4 __attribute__((ext_vector_type(4)));

#define WS_WT_OFF  0            // WT2 : 8 MB, q-major fragment order
#define WS_XF_OFF  8388608      // Xf  : 1 MB, x f16 seg-XOR
#define WS_X0_OFF  9437184      // X0T2: 1 MB, x0 f16 [mb64][row][f] swizzled
#define WS_NEEDED  10485760

__device__ __forceinline__ void gl_lds16(const void* g, void* l) {
  __builtin_amdgcn_global_load_lds(
      (const __attribute__((address_space(1))) void*)g,
      (__attribute__((address_space(3))) void*)l, 16, 0, 0);
}

// ------------------------------ prep kernel --------------------------------
// [0,524288): W f32->f16, q-major window order:
//   ks=k8>>2 g=k8&3; sv=ks>>6; r=ks&63; f=r>>2; q=r&3;
//   WT2 f16 idx = ((oq*512 + sv*64 + q*16+f)*4 + g)*512 + (o&63)*8, oq=o>>6.
// [524288,589824): x f32->f16 + 16B-seg XOR keyed row&7.
// [589824,655360): x0 f16 [mb64][row(64)][f(128)], 16B f-blocks XOR'd row&7.
// [655360,917504): out = bias (float4 groups).
__global__ __launch_bounds__(256) void prep_kernel(
    const float* __restrict__ x0, const float* __restrict__ x,
    const float* __restrict__ W, const float* __restrict__ bias,
    _Float16* __restrict__ WT2, _Float16* __restrict__ Xf,
    _Float16* __restrict__ X0T2, float* __restrict__ out)
{
  int i = blockIdx.x * 256 + threadIdx.x;
  if (i < 524288) {
    int o = i >> 11, k8 = i & 2047;
    const float* s = W + ((size_t)o << 14) + ((size_t)k8 << 3);
    f16x8 h;
#pragma unroll
    for (int e = 0; e < 8; ++e) h[e] = (_Float16)s[e];
    int ks = k8 >> 2, g = k8 & 3, oq = o >> 6, o6 = o & 63;
    int sv = ks >> 6, r = ks & 63, f = r >> 2, q = r & 3;
    *(f16x8*)(WT2 + ((size_t)((oq * 512 + sv * 64 + q * 16 + f) * 4 + g)) * 512 +
              o6 * 8) = h;
  } else if (i < 589824) {
    int j = i - 524288;
    int r = j >> 4, seg = j & 15;
    const float* s = x + r * 128 + seg * 8;
    f16x8 h;
#pragma unroll
    for (int e = 0; e < 8; ++e) h[e] = (_Float16)s[e];
    int segp = seg ^ (r & 7);
    *(f16x8*)(Xf + r * 128 + segp * 8) = h;
  } else if (i < 655360) {
    int j = i - 589824;                // (mb64, row, 8-f block)
    int mb = j >> 10, rem = j & 1023;
    int row = rem >> 4, jb = rem & 15;
    f16x8 h;
#pragma unroll
    for (int e = 0; e < 8; ++e)
      h[e] = (_Float16)x0[(size_t)(mb * 64 + row) * 128 + jb * 8 + e];
    *(f16x8*)(X0T2 + (size_t)mb * 8192 + row * 128 + (jb ^ (row & 7)) * 8) = h;
  } else {
    int j = i - 655360;                // float4 idx into out[4096][256]
    int c = (j * 4) & 255;
    ((float4*)out)[j] = *(const float4*)(bias + c);
  }
}

// ------------------------------ GEMM kernel --------------------------------
// smem: [0,16384) x_s [64r][128p] f16 swz; [16384,32768) x0t [64r][128f] swz.
// Tables used only to fill registers in the prologue.
__global__ __launch_bounds__(256, 1) void gemm_kernel(
    const _Float16* __restrict__ WT2, const _Float16* __restrict__ Xf,
    const _Float16* __restrict__ X0T2, float* __restrict__ out)
{
  __shared__ __align__(16) char smem[32768];

  const int bid = blockIdx.x;
  const int mb  = bid >> 2;          // 0..63 : 64-row block
  const int sk  = bid & 3;           // 0..3  : K-quarter (4096 k) -> XCD

  const int t   = threadIdx.x;
  const int l   = t & 63;
  const int wn  = t >> 6;            // wave = o-quarter owner
  const int lr  = l & 15;
  const int lg  = l >> 4;
  const int swz = lr & 7;
  const int wofs = lg * 1024 + lr * 16;

  // wave W stream: o-quarter wn, windows sk*128 .. sk*128+127 (contiguous)
  const char* wsrc = (const char*)WT2 + ((size_t)(wn * 512 + sk * 128)) * 4096;

  // ---- prologue: tables -> LDS (one-time) ----
  const char* xsb = (const char*)Xf + (size_t)mb * 16384;
#pragma unroll
  for (int i = 0; i < 4; ++i)
    gl_lds16(xsb + i * 4096 + t * 16, smem + i * 4096 + t * 16);
  const char* x0b = (const char*)X0T2 + (size_t)mb * 16384;
#pragma unroll
  for (int i = 0; i < 4; ++i)
    gl_lds16(x0b + i * 4096 + t * 16, smem + 16384 + i * 4096 + t * 16);
  __syncthreads();

  // ---- register state: ALL q A-fragments, acc, 4-deep B ring ----
  f16x8 xa[4][4];                     // [q][m] — static indices only
#pragma unroll
  for (int q = 0; q < 4; ++q)
#pragma unroll
    for (int m = 0; m < 4; ++m)
      xa[q][m] = *(const f16x8*)(smem + (m * 16 + lr) * 256 +
                                 (((q * 4 + lg) ^ swz) << 4));
  f16x8 x0v[2][4];                    // [f-octet][m] — reloaded per sv
  f32x4 acc[4][4] = {};
  f16x8 bw0[4], bw1[4], bw2[4], bw3[4];

  // prime windows 0..2
#pragma unroll
  for (int i = 0; i < 4; ++i)
    bw0[i] = *(const f16x8*)(wsrc + 0 * 4096 + i * 256 + wofs);
#pragma unroll
  for (int i = 0; i < 4; ++i)
    bw1[i] = *(const f16x8*)(wsrc + 1 * 4096 + i * 256 + wofs);
#pragma unroll
  for (int i = 0; i < 4; ++i)
    bw2[i] = *(const f16x8*)(wsrc + 2 * 4096 + i * 256 + wofs);

  // STEP(WI, BR, BW_): stage window WI+3 -> BW_; 16 MFMA from BR.
  // q=(WI>>4)&3, f-octet=(WI>>3)&1, elem=WI&7 — all literal.
#define STEP(WI, BR, BW_) { \
    _Pragma("unroll") \
    for (int i = 0; i < 4; ++i) \
      BW_[i] = *(const f16x8*)(wcur + ((WI) + 3) * 4096 + i * 256 + wofs); \
    f16x8 av[4]; \
    _Pragma("unroll") \
    for (int m = 0; m < 4; ++m) \
      av[m] = xa[((WI) >> 4) & 3][m] * x0v[((WI) >> 3) & 1][m][(WI) & 7]; \
    _Pragma("unroll") \
    for (int m = 0; m < 4; ++m) { \
      _Pragma("unroll") \
      for (int n = 0; n < 4; ++n) \
        acc[m][n] = __builtin_amdgcn_mfma_f32_16x16x32_f16( \
            av[m], BR[n], acc[m][n], 0, 0, 0); \
    } \
  }

#define T0(WI) STEP(WI, bw0, bw3)
#define T1(WI) STEP(WI, bw1, bw0)
#define T2(WI) STEP(WI, bw2, bw1)
#define T3(WI) STEP(WI, bw3, bw2)

  const char* wcur = wsrc;
  for (int sv2 = 0; sv2 < 2; ++sv2) {
    const int svg = sk * 2 + sv2;     // global sv slice (f svg*16..+15)
#pragma unroll
    for (int h = 0; h < 2; ++h)
#pragma unroll
      for (int m = 0; m < 4; ++m)
        x0v[h][m] = *(const f16x8*)(smem + 16384 + (m * 16 + lr) * 256 +
                                    (((svg * 2 + h) ^ swz) << 4));
    T0(0)  T1(1)  T2(2)  T3(3)  T0(4)  T1(5)  T2(6)  T3(7)
    T0(8)  T1(9)  T2(10) T3(11) T0(12) T1(13) T2(14) T3(15)
    T0(16) T1(17) T2(18) T3(19) T0(20) T1(21) T2(22) T3(23)
    T0(24) T1(25) T2(26) T3(27) T0(28) T1(29) T2(30) T3(31)
    T0(32) T1(33) T2(34) T3(35) T0(36) T1(37) T2(38) T3(39)
    T0(40) T1(41) T2(42) T3(43) T0(44) T1(45) T2(46) T3(47)
    T0(48) T1(49) T2(50) T3(51) T0(52) T1(53) T2(54) T3(55)
    T0(56) T1(57) T2(58) T3(59) T0(60) T1(61) T2(62) T3(63)
    wcur += 64 * 4096;
    // final-iteration overshoot (windows 128..130) lands in the Xf region
    // of ws — valid memory, values never consumed.
  }
#undef T0
#undef T1
#undef T2
#undef T3
#undef STEP

  // ---- epilogue: split-K-4 accumulate (out pre-initialized to bias) ----
  // C/D layout: col = lane&15, row = (lane>>4)*4 + reg
  float* op = out + (size_t)(mb * 64 + lg * 4) * 256 + wn * 64 + lr;
#pragma unroll
  for (int m = 0; m < 4; ++m)
#pragma unroll
    for (int n = 0; n < 4; ++n)
#pragma unroll
      for (int rr = 0; rr < 4; ++rr)
        unsafeAtomicAdd(op + (size_t)(m * 16 + rr) * 256 + n * 16,
                        acc[m][n][rr]);
}

// --------------------------- fallback (no ws) ------------------------------
__global__ __launch_bounds__(256) void naive_kernel(
    const float* __restrict__ x0, const float* __restrict__ x,
    const float* __restrict__ W, const float* __restrict__ bias,
    float* __restrict__ out)
{
  __shared__ float x0_s[16][128];
  __shared__ float x_s[16][128];
  const int tid = threadIdx.x;
  const int b0  = blockIdx.x * 16;
  for (int i = tid; i < 16 * 128; i += 256) {
    int bb = i >> 7, c = i & 127;
    x0_s[bb][c] = x0[(size_t)(b0 + bb) * 128 + c];
    x_s[bb][c]  = x[(size_t)(b0 + bb) * 128 + c];
  }
  __syncthreads();
  const int lane = tid & 63, wv = tid >> 6;
  for (int o = wv; o < 256; o += 4) {
    float acc[16];
#pragma unroll
    for (int bb = 0; bb < 16; ++bb) acc[bb] = 0.f;
    for (int it = 0; it < 256; ++it) {
      int k = it * 64 + lane;
      float wval = W[(size_t)o * 16384 + k];
      int f = k >> 7, p = k & 127;
#pragma unroll
      for (int bb = 0; bb < 16; ++bb)
        acc[bb] += wval * (x0_s[bb][f] * x_s[bb][p]);
    }
#pragma unroll
    for (int bb = 0; bb < 16; ++bb) {
      float v = acc[bb];
      for (int off = 32; off; off >>= 1) v += __shfl_down(v, off);
      if (lane == 0) out[(size_t)(b0 + bb) * 256 + o] = v + bias[o];
    }
  }
}

// ------------------------------- launcher ----------------------------------
extern "C" void kernel_launch(void* const* d_in, const int* in_sizes, int n_in,
                              void* d_out, int out_size, void* d_ws,
                              size_t ws_size, hipStream_t stream)
{
  const float* x0   = (const float*)d_in[0];
  const float* x    = (const float*)d_in[1];
  const float* W    = (const float*)d_in[2];
  const float* bias = (const float*)d_in[3];
  float* out = (float*)d_out;

  if (ws_size >= (size_t)WS_NEEDED) {
    _Float16* WT2  = (_Float16*)((char*)d_ws + WS_WT_OFF);
    _Float16* Xf   = (_Float16*)((char*)d_ws + WS_XF_OFF);
    _Float16* X0T2 = (_Float16*)((char*)d_ws + WS_X0_OFF);
    prep_kernel<<<3584, 256, 0, stream>>>(x0, x, W, bias, WT2, Xf, X0T2, out);
    gemm_kernel<<<256, 256, 0, stream>>>(WT2, Xf, X0T2, out);
  } else {
    naive_kernel<<<256, 256, 0, stream>>>(x0, x, W, bias, out);
  }
}

// Round 16
// 73.851 us; speedup vs baseline: 1.1865x; 1.1865x over previous
//
#include <hip/hip_runtime.h>

// ---------------------------------------------------------------------------
// out[b,o] = sum_{f,p} x0[b,f]*x[b,p]*W[o,f,p] + bias[o]
//   == GEMM C[4096,256] = A[4096,16384] * W^T,  A[b,f*128+p] = x0[b,f]*x[b,p]
// R16: m201-faithful phase schedule on the R7 chassis. Session lesson: the
// allocator only tolerates large state in the AGPR accumulator; A/B must be
// transient-from-LDS (all register-resident designs got demoted: R8/9/14/15).
// BM=128 BN=256 BK=64, 512thr/8 waves (2m x 4n, wave 64x64, acc 64 AGPR).
// Per K-step: 2 phases of {8 ds_read (4A+4B, XOR-swizzle-clean) ; 2 gl_lds
// stage rounds for step+2 -> literal ring slot ; s_barrier ; lgkmcnt(0) ;
// setprio(1) ; 16 MFMA ; setprio(0)} ; vmcnt(4) once per step (never 0).
// Ring slots fully literal (R3's runtime-offset defect fixed; R6/R7-proven
// 6-step unroll). x persistent 32KB LDS; x0 via 4KB LDS table. Grid 256 =
// 32mb x 8sk (sk=bid&7 -> XCD-L2-resident 1MB W slice). Split-K-8 f32
// atomics onto bias-pre-initialized out (R7-proven rate).
// ---------------------------------------------------------------------------

typedef _Float16 f16x8 __attribute__((ext_vector_type(8)));
typedef float    f32x4 __attribute__((ext_vector_type(4)));

#define WS_WF_OFF  0            // Wf : 8 MB, row-major + seg-XOR (R7 layout)
#define WS_XF_OFF  8388608      // Xf : 1 MB, x f16 seg-XOR (R7 layout)
#define WS_X0_OFF  9437184      // X0F: 1 MB, x0 f16 transposed [128 f][4096 b]
#define WS_NEEDED  10485760

__device__ __forceinline__ void gl_lds16(const void* g, void* l) {
  __builtin_amdgcn_global_load_lds(
      (const __attribute__((address_space(1))) void*)g,
      (__attribute__((address_space(3))) void*)l, 16, 0, 0);
}

#define VMC4 asm volatile("s_waitcnt vmcnt(4)" ::: "memory");
#define VMC0 asm volatile("s_waitcnt vmcnt(0)" ::: "memory");

// ------------------------------ prep kernel --------------------------------
// [0,524288): W f32->f16 row-major [256][16384] + XOR seg-swizzle within each
//   64-k window, key o&7 (R7-proven). [524288,589824): x f32->f16 + seg-XOR
//   keyed row&7. [589824,655360): x0 -> X0F f16 [128 f][4096 b] (coalesced
//   writes, gathered reads). [655360,917504): out = bias (float4 groups).
__global__ __launch_bounds__(256) void prep_kernel(
    const float* __restrict__ x0, const float* __restrict__ x,
    const float* __restrict__ W, const float* __restrict__ bias,
    _Float16* __restrict__ Wf, _Float16* __restrict__ Xf,
    _Float16* __restrict__ X0F, float* __restrict__ out)
{
  int i = blockIdx.x * 256 + threadIdx.x;
  if (i < 524288) {
    int o = i >> 11, k8 = i & 2047;
    int kk = k8 >> 3, seg = k8 & 7;
    const float* s = W + ((size_t)o << 14) + ((size_t)k8 << 3);
    f16x8 h;
#pragma unroll
    for (int e = 0; e < 8; ++e) h[e] = (_Float16)s[e];
    int segp = seg ^ (o & 7);
    *(f16x8*)(Wf + ((size_t)o << 14) + kk * 64 + segp * 8) = h;
  } else if (i < 589824) {
    int j = i - 524288;
    int r = j >> 4, seg = j & 15;
    const float* s = x + r * 128 + seg * 8;
    f16x8 h;
#pragma unroll
    for (int e = 0; e < 8; ++e) h[e] = (_Float16)s[e];
    int segp = seg ^ (r & 7);
    *(f16x8*)(Xf + r * 128 + segp * 8) = h;
  } else if (i < 655360) {
    int j = i - 589824;                // f = j>>9, 8-b block = j&511
    int f = j >> 9, b8 = j & 511;
    f16x8 h;
#pragma unroll
    for (int e = 0; e < 8; ++e)
      h[e] = (_Float16)x0[(size_t)(b8 * 8 + e) * 128 + f];
    *(f16x8*)(X0F + (size_t)f * 4096 + b8 * 8) = h;
  } else {
    int j = i - 655360;                // float4 idx into out[4096][256]
    int c = (j * 4) & 255;
    ((float4*)out)[j] = *(const float4*)(bias + c);
  }
}

// ------------------------------ GEMM kernel --------------------------------
// smem: [0,32768) x_s [128 r][128 p] f16 swz; slot i at 32768+i*32768
// (3 x 32 KB W [256 o][64 k] f16 swz); [131072,135168) x0t f16 [16 f][128 r].
__global__ __launch_bounds__(512) void gemm_kernel(
    const _Float16* __restrict__ Wf, const _Float16* __restrict__ Xf,
    const _Float16* __restrict__ X0F, float* __restrict__ out)
{
  __shared__ __align__(16) char smem[135168];
#define WSLOT(i) (smem + 32768 + (i) * 32768)

  const int bid = blockIdx.x;
  const int mb  = bid >> 3;          // 0..31 : 128-row block
  const int sk  = bid & 7;           // 0..7  : split-K chunk -> XCD

  const int t   = threadIdx.x;
  const int l   = t & 63;
  const int wv  = t >> 6;
  const int wm  = wv >> 2;           // 0..1 : 64-row half
  const int wn  = wv & 3;            // 0..3 : 64-o quarter
  const int lr  = l & 15;
  const int lg  = l >> 4;
  const int swz = lr & 7;

  const char* WfB  = (const char*)Wf;
  const int  kbase = sk * 4096;      // byte offset of chunk's k-window in row
  const int  xrb   = (wm * 64 + lr) * 256;
  const int  brow  = (wn * 64 + lr) * 128;

  // ---- prologue: x (4 rounds), x0t (1 round), W steps 0,1 (8 rounds) ----
  const char* xsb = (const char*)Xf + (size_t)mb * 32768;
#pragma unroll
  for (int i = 0; i < 4; ++i)
    gl_lds16(xsb + i * 8192 + t * 16, smem + i * 8192 + t * 16);
  if (t < 256) {
    const char* s0 = (const char*)X0F +
        (size_t)(sk * 16 + (t >> 4)) * 8192 + mb * 256 + (t & 15) * 16;
    gl_lds16(s0, smem + 131072 + t * 16);
  }
#pragma unroll
  for (int i = 0; i < 4; ++i) {
    int d = i * 8192 + t * 16;
    gl_lds16(WfB + (size_t)(d >> 7) * 32768 + kbase + 0 * 128 + (d & 127),
             WSLOT(0) + d);
  }
#pragma unroll
  for (int i = 0; i < 4; ++i) {
    int d = i * 8192 + t * 16;
    gl_lds16(WfB + (size_t)(d >> 7) * 32768 + kbase + 1 * 128 + (d & 127),
             WSLOT(1) + d);
  }
  VMC0;
  __syncthreads();

  f32x4 acc[4][4] = {};
  _Float16 sh[4];

  // PHASE: operand reads + stage issue BEFORE barrier; MFMA cluster after
  // lgkmcnt(0); vmcnt(4) only at step end (never 0 in main loop).
#define PHASE(S, KK, PAR, RD, ST, STG, SHL, VM) { \
    if (SHL) { \
      _Pragma("unroll") \
      for (int m = 0; m < 4; ++m) \
        sh[m] = *(const _Float16*)(smem + 131072 + \
                 (((S) >> 1) * 128 + wm * 64 + m * 16 + lr) * 2); \
    } \
    f16x8 bw[4], av[4]; \
    _Pragma("unroll") \
    for (int n = 0; n < 4; ++n) \
      bw[n] = *(const f16x8*)(WSLOT(RD) + brow + n * 2048 + \
                              ((((KK) * 4 + lg) ^ swz) << 4)); \
    _Pragma("unroll") \
    for (int m = 0; m < 4; ++m) \
      av[m] = *(const f16x8*)(smem + xrb + m * 4096 + \
               ((((PAR) * 8 + (KK) * 4 + lg) ^ swz) << 4)) * sh[m]; \
    if (STG) { \
      _Pragma("unroll") \
      for (int i = (KK) * 2; i < (KK) * 2 + 2; ++i) { \
        int d = i * 8192 + t * 16; \
        gl_lds16(WfB + (size_t)(d >> 7) * 32768 + kbase + ((S) + 2) * 128 + (d & 127), \
                 WSLOT(ST) + d); \
      } \
    } \
    __builtin_amdgcn_s_barrier(); \
    asm volatile("s_waitcnt lgkmcnt(0)" ::: "memory"); \
    __builtin_amdgcn_s_setprio(1); \
    _Pragma("unroll") \
    for (int m = 0; m < 4; ++m) { \
      _Pragma("unroll") \
      for (int n = 0; n < 4; ++n) \
        acc[m][n] = __builtin_amdgcn_mfma_f32_16x16x32_f16( \
            av[m], bw[n], acc[m][n], 0, 0, 0); \
    } \
    __builtin_amdgcn_s_setprio(0); \
    VM \
    __builtin_amdgcn_s_barrier(); \
}

#define STEP6(B_) \
  PHASE(B_+0, 0, 0, 0, 2, 1, 1, ;) PHASE(B_+0, 1, 0, 0, 2, 1, 0, VMC4) \
  PHASE(B_+1, 0, 1, 1, 0, 1, 0, ;) PHASE(B_+1, 1, 1, 1, 0, 1, 0, VMC4) \
  PHASE(B_+2, 0, 0, 2, 1, 1, 1, ;) PHASE(B_+2, 1, 0, 2, 1, 1, 0, VMC4) \
  PHASE(B_+3, 0, 1, 0, 2, 1, 0, ;) PHASE(B_+3, 1, 1, 0, 2, 1, 0, VMC4) \
  PHASE(B_+4, 0, 0, 1, 0, 1, 1, ;) PHASE(B_+4, 1, 0, 1, 0, 1, 0, VMC4) \
  PHASE(B_+5, 0, 1, 2, 1, 1, 0, ;) PHASE(B_+5, 1, 1, 2, 1, 1, 0, VMC4)

  for (int k3 = 0; k3 < 30; k3 += 6) {
    STEP6(k3)
  }
  // tail: steps 30 (RD 0) and 31 (RD 1), no staging
  PHASE(30, 0, 0, 0, 0, 0, 1, ;) PHASE(30, 1, 0, 0, 0, 0, 0, VMC0)
  PHASE(31, 0, 1, 1, 0, 0, 0, ;) PHASE(31, 1, 1, 1, 0, 0, 0, ;)

#undef STEP6
#undef PHASE
#undef WSLOT

  // ---- epilogue: split-K-8 accumulate (out pre-initialized to bias) ----
  // C/D layout: col = lane&15, row = (lane>>4)*4 + reg
  float* op = out + (size_t)(mb * 128 + wm * 64 + lg * 4) * 256 + wn * 64 + lr;
#pragma unroll
  for (int m = 0; m < 4; ++m)
#pragma unroll
    for (int n = 0; n < 4; ++n)
#pragma unroll
      for (int rr = 0; rr < 4; ++rr)
        unsafeAtomicAdd(op + (size_t)(m * 16 + rr) * 256 + n * 16,
                        acc[m][n][rr]);
}

// --------------------------- fallback (no ws) ------------------------------
__global__ __launch_bounds__(256) void naive_kernel(
    const float* __restrict__ x0, const float* __restrict__ x,
    const float* __restrict__ W, const float* __restrict__ bias,
    float* __restrict__ out)
{
  __shared__ float x0_s[16][128];
  __shared__ float x_s[16][128];
  const int tid = threadIdx.x;
  const int b0  = blockIdx.x * 16;
  for (int i = tid; i < 16 * 128; i += 256) {
    int bb = i >> 7, c = i & 127;
    x0_s[bb][c] = x0[(size_t)(b0 + bb) * 128 + c];
    x_s[bb][c]  = x[(size_t)(b0 + bb) * 128 + c];
  }
  __syncthreads();
  const int lane = tid & 63, wv = tid >> 6;
  for (int o = wv; o < 256; o += 4) {
    float acc[16];
#pragma unroll
    for (int bb = 0; bb < 16; ++bb) acc[bb] = 0.f;
    for (int it = 0; it < 256; ++it) {
      int k = it * 64 + lane;
      float wval = W[(size_t)o * 16384 + k];
      int f = k >> 7, p = k & 127;
#pragma unroll
      for (int bb = 0; bb < 16; ++bb)
        acc[bb] += wval * (x0_s[bb][f] * x_s[bb][p]);
    }
#pragma unroll
    for (int bb = 0; bb < 16; ++bb) {
      float v = acc[bb];
      for (int off = 32; off; off >>= 1) v += __shfl_down(v, off);
      if (lane == 0) out[(size_t)(b0 + bb) * 256 + o] = v + bias[o];
    }
  }
}

// ------------------------------- launcher ----------------------------------
extern "C" void kernel_launch(void* const* d_in, const int* in_sizes, int n_in,
                              void* d_out, int out_size, void* d_ws,
                              size_t ws_size, hipStream_t stream)
{
  const float* x0   = (const float*)d_in[0];
  const float* x    = (const float*)d_in[1];
  const float* W    = (const float*)d_in[2];
  const float* bias = (const float*)d_in[3];
  float* out = (float*)d_out;

  if (ws_size >= (size_t)WS_NEEDED) {
    _Float16* Wf  = (_Float16*)((char*)d_ws + WS_WF_OFF);
    _Float16* Xf  = (_Float16*)((char*)d_ws + WS_XF_OFF);
    _Float16* X0F = (_Float16*)((char*)d_ws + WS_X0_OFF);
    prep_kernel<<<3584, 256, 0, stream>>>(x0, x, W, bias, Wf, Xf, X0F, out);
    gemm_kernel<<<256, 512, 0, stream>>>(Wf, Xf, X0F, out);
  } else {
    naive_kernel<<<256, 256, 0, stream>>>(x0, x, W, bias, out);
  }
}

// Round 17
// 49.039 us; speedup vs baseline: 1.7868x; 1.5060x over previous
//
#include <hip/hip_runtime.h>

// ---------------------------------------------------------------------------
// out[b,o] = sum_{f,p} x0[b,f]*x[b,p]*W[o,f,p] + bias[o]
//   == GEMM C[4096,256] = A[4096,16384] * W^T,  A[b,f*128+p] = x0[b,f]*x[b,p]
// R17 = R12 verbatim (session best: 49.28us total, gemm ~41us ~ 840 GF).
// Rationale: six structural families explored (2-phase LDS, 8-phase counted
// vmcnt, wave-private rings, register-stream, 4-wave/SIMD occupancy, full
// ILP residency) all converge to gemm 41-57us with no pipe saturated —
// latency-bound at the 128-VGPR/2-wave-SIMD allocation frontier (plain-HIP
// structural plateau; beyond needs hand-asm scheduling). Restoring best.
//
// Structure: barrier-free K-loop. Each wave owns 64r x 64o x 2048k as 64
// q-major windows (64o x 32k = 4KB, 4 coalesced dwordx4); B streamed
// L2->registers through a named 3-buffer ring (literal rotation); A is
// rank-1-reconstructed from 32 persistent regs (xa[4] + x0v[4], q-major
// order makes reloads 1-per-16-windows); compiler-scheduled vmcnt; zero
// barriers/asm/LDS ops in the loop. Grid 256 = 64mb x 4ob; ob=bid&3 pins
// each XCD to a 2MB L2-resident W slice. Epilogue: in-block LDS reduce of
// the 8 wave partials + plain coalesced f32+bias stores (no atomics).
// ---------------------------------------------------------------------------

typedef _Float16 f16x8 __attribute__((ext_vector_type(8)));
typedef float    f32x4 __attribute__((ext_vector_type(4)));

#define WS_WT_OFF  0            // WT2 : 8 MB, q-major fragment order
#define WS_XF_OFF  8388608      // Xf  : 1 MB, x f16 seg-XOR (R7 layout)
#define WS_X0_OFF  9437184      // X0T2: 1 MB, x0 f16 [mb][row][f] swizzled
#define WS_NEEDED  10485760

__device__ __forceinline__ void gl_lds16(const void* g, void* l) {
  __builtin_amdgcn_global_load_lds(
      (const __attribute__((address_space(1))) void*)g,
      (__attribute__((address_space(3))) void*)l, 16, 0, 0);
}

// ------------------------------ prep kernel --------------------------------
// [0,524288): W f32->f16, q-major window order. k8 granule: ks=k8>>2 g=k8&3;
//   wv=ks>>6; r=ks&63; f=r>>2; q=r&3; widx=q*16+f;
//   WT2 f16 idx = ((ob*512 + wv*64 + widx)*4 + g)*512 + (o&63)*8.
// [524288,589824): x f32->f16 + 16B-seg XOR keyed row&7.
// [589824,655360): x0 f16 [mb][row(64)][f(128)], 16B f-blocks XOR'd by row&7.
__global__ __launch_bounds__(256) void prep_kernel(
    const float* __restrict__ x0, const float* __restrict__ x,
    const float* __restrict__ W, _Float16* __restrict__ WT2,
    _Float16* __restrict__ Xf, _Float16* __restrict__ X0T2)
{
  int i = blockIdx.x * 256 + threadIdx.x;
  if (i < 524288) {
    int o = i >> 11, k8 = i & 2047;
    const float* s = W + ((size_t)o << 14) + ((size_t)k8 << 3);
    f16x8 h;
#pragma unroll
    for (int e = 0; e < 8; ++e) h[e] = (_Float16)s[e];
    int ks = k8 >> 2, g = k8 & 3, ob = o >> 6, o6 = o & 63;
    int wv = ks >> 6, r = ks & 63, f = r >> 2, q = r & 3;
    int widx = q * 16 + f;
    *(f16x8*)(WT2 + ((size_t)((ob * 512 + wv * 64 + widx) * 4 + g)) * 512 +
              o6 * 8) = h;
  } else if (i < 589824) {
    int j = i - 524288;
    int r = j >> 4, seg = j & 15;
    const float* s = x + r * 128 + seg * 8;
    f16x8 h;
#pragma unroll
    for (int e = 0; e < 8; ++e) h[e] = (_Float16)s[e];
    int segp = seg ^ (r & 7);
    *(f16x8*)(Xf + r * 128 + segp * 8) = h;
  } else {
    int j = i - 589824;                // (mb, row, 8-f block)
    int mb = j >> 10, rem = j & 1023;
    int row = rem >> 4, jb = rem & 15;
    f16x8 h;
#pragma unroll
    for (int e = 0; e < 8; ++e)
      h[e] = (_Float16)x0[(size_t)(mb * 64 + row) * 128 + jb * 8 + e];
    *(f16x8*)(X0T2 + (size_t)mb * 8192 + row * 128 + (jb ^ (row & 7)) * 8) = h;
  }
}

// ------------------------------ GEMM kernel --------------------------------
// smem compute: [0,16384) x_s [64r][128p] swz; [16384,32768) x0 [64r][128f]
// swz. Epilogue reuses [0,139264): 8 regions x 17408 B.
__global__ __launch_bounds__(512, 2) void gemm_kernel(
    const _Float16* __restrict__ WT2, const _Float16* __restrict__ Xf,
    const _Float16* __restrict__ X0T2, const float* __restrict__ bias,
    float* __restrict__ out)
{
  __shared__ __align__(16) char smem[139264];

  const int bid = blockIdx.x;
  const int mb  = bid >> 2;          // 0..63 : 64-row block
  const int ob  = bid & 3;           // 0..3  : 64-o block (== bid%8&3 -> XCD)

  const int t  = threadIdx.x;
  const int l  = t & 63;
  const int wv = t >> 6;             // wave = k-chunk owner (f wv*16..+15)
  const int lr = l & 15;
  const int lg = l >> 4;
  const int swz = lr & 7;

  const char* wsrc = (const char*)WT2 + ((size_t)(ob * 512 + wv * 64)) * 4096;
  const int wofs = lg * 1024 + lr * 16;   // lane offset within a window

  // ---- prologue: x_s + x0 tables -> LDS (one-time), A-state -> regs ----
  const char* xsb = (const char*)Xf + (size_t)mb * 16384;
  gl_lds16(xsb + 0 * 8192 + t * 16, smem + 0 * 8192 + t * 16);
  gl_lds16(xsb + 1 * 8192 + t * 16, smem + 1 * 8192 + t * 16);
  const char* x0b = (const char*)X0T2 + (size_t)mb * 16384;
  gl_lds16(x0b + 0 * 8192 + t * 16, smem + 16384 + 0 * 8192 + t * 16);
  gl_lds16(x0b + 1 * 8192 + t * 16, smem + 16384 + 1 * 8192 + t * 16);
  __syncthreads();

  f32x4 acc[4][4] = {};
  f16x8 xa[4], x0v[4], bw0[4], bw1[4], bw2[4];

#pragma unroll
  for (int m = 0; m < 4; ++m)
    xa[m] = *(const f16x8*)(smem + (m * 16 + lr) * 256 + ((lg ^ swz) << 4));
#pragma unroll
  for (int m = 0; m < 4; ++m)
    x0v[m] = *(const f16x8*)(smem + 16384 + (m * 16 + lr) * 256 +
                             (((wv * 2) ^ swz) << 4));
  // prime: windows 0,1 -> bw0,bw1 (plain loads; compiler counts vmcnt)
#pragma unroll
  for (int i = 0; i < 4; ++i)
    bw0[i] = *(const f16x8*)(wsrc + 0 * 4096 + i * 256 + wofs);
#pragma unroll
  for (int i = 0; i < 4; ++i)
    bw1[i] = *(const f16x8*)(wsrc + 1 * 4096 + i * 256 + wofs);

  // STEP(WI, BR, BW_, STG): issue window WI+2 -> BW_ ring buf, boundary
  // xa/x0v reloads (for WI+1), 16 MFMA from BR. No asm, no barriers.
#define STEP(WI, BR, BW_, STG) { \
    if (STG) { \
      _Pragma("unroll") \
      for (int i = 0; i < 4; ++i) \
        BW_[i] = *(const f16x8*)(wsrc + ((WI) + 2) * 4096 + i * 256 + wofs); \
    } \
    f16x8 av[4]; \
    _Pragma("unroll") \
    for (int m = 0; m < 4; ++m) \
      av[m] = xa[m] * x0v[m][(WI) & 7]; \
    if ((((WI) + 1) & 15) == 0 && (WI) < 63) { \
      _Pragma("unroll") \
      for (int m = 0; m < 4; ++m) \
        xa[m] = *(const f16x8*)(smem + (m * 16 + lr) * 256 + \
                 ((((((WI) + 1) >> 4) * 4 + lg) ^ swz) << 4)); \
    } \
    if ((((WI) + 1) & 7) == 0 && (WI) < 63) { \
      _Pragma("unroll") \
      for (int m = 0; m < 4; ++m) \
        x0v[m] = *(const f16x8*)(smem + 16384 + (m * 16 + lr) * 256 + \
                  (((wv * 2 + ((((WI) + 1) >> 3) & 1)) ^ swz) << 4)); \
    } \
    _Pragma("unroll") \
    for (int m = 0; m < 4; ++m) { \
      _Pragma("unroll") \
      for (int n = 0; n < 4; ++n) \
        acc[m][n] = __builtin_amdgcn_mfma_f32_16x16x32_f16( \
            av[m], BR[n], acc[m][n], 0, 0, 0); \
    } \
  }

#define S0(WI, STG) STEP(WI, bw0, bw2, STG)
#define S1(WI, STG) STEP(WI, bw1, bw0, STG)
#define S2(WI, STG) STEP(WI, bw2, bw1, STG)

  S0(0,1)  S1(1,1)  S2(2,1)  S0(3,1)  S1(4,1)  S2(5,1)
  S0(6,1)  S1(7,1)  S2(8,1)  S0(9,1)  S1(10,1) S2(11,1)
  S0(12,1) S1(13,1) S2(14,1) S0(15,1) S1(16,1) S2(17,1)
  S0(18,1) S1(19,1) S2(20,1) S0(21,1) S1(22,1) S2(23,1)
  S0(24,1) S1(25,1) S2(26,1) S0(27,1) S1(28,1) S2(29,1)
  S0(30,1) S1(31,1) S2(32,1) S0(33,1) S1(34,1) S2(35,1)
  S0(36,1) S1(37,1) S2(38,1) S0(39,1) S1(40,1) S2(41,1)
  S0(42,1) S1(43,1) S2(44,1) S0(45,1) S1(46,1) S2(47,1)
  S0(48,1) S1(49,1) S2(50,1) S0(51,1) S1(52,1) S2(53,1)
  S0(54,1) S1(55,1) S2(56,1) S0(57,1) S1(58,1) S2(59,1)
  S0(60,1) S1(61,1) S2(62,0) S0(63,0)

#undef S0
#undef S1
#undef S2
#undef STEP

  // ---- epilogue: LDS reduce of 8 partials, plain f32 store (no atomics) ---
  __syncthreads();                     // all waves done reading x_s/x0 LDS

  // region wv: [col(64) x 272B][row(64) f32]
#pragma unroll
  for (int m = 0; m < 4; ++m)
#pragma unroll
    for (int n = 0; n < 4; ++n)
      *(f32x4*)(smem + wv * 17408 + (n * 16 + lr) * 272 +
                (m * 16 + lg * 4) * 4) = acc[m][n];

  __syncthreads();

  {
    const int row = t >> 3, c8 = (t & 7) * 8;
    float v[8];
#pragma unroll
    for (int c = 0; c < 8; ++c) {
      float s = 0.f;
#pragma unroll
      for (int w = 0; w < 8; ++w)
        s += *(const float*)(smem + w * 17408 + (c8 + c) * 272 + row * 4);
      v[c] = s;
    }
    const float4 b0 = *(const float4*)(bias + ob * 64 + c8);
    const float4 b1 = *(const float4*)(bias + ob * 64 + c8 + 4);
    float* op = out + (size_t)(mb * 64 + row) * 256 + ob * 64 + c8;
    float4 o0 = {v[0] + b0.x, v[1] + b0.y, v[2] + b0.z, v[3] + b0.w};
    float4 o1 = {v[4] + b1.x, v[5] + b1.y, v[6] + b1.z, v[7] + b1.w};
    *(float4*)(op)     = o0;
    *(float4*)(op + 4) = o1;
  }
}

// --------------------------- fallback (no ws) ------------------------------
__global__ __launch_bounds__(256) void naive_kernel(
    const float* __restrict__ x0, const float* __restrict__ x,
    const float* __restrict__ W, const float* __restrict__ bias,
    float* __restrict__ out)
{
  __shared__ float x0_s[16][128];
  __shared__ float x_s[16][128];
  const int tid = threadIdx.x;
  const int b0  = blockIdx.x * 16;
  for (int i = tid; i < 16 * 128; i += 256) {
    int bb = i >> 7, c = i & 127;
    x0_s[bb][c] = x0[(size_t)(b0 + bb) * 128 + c];
    x_s[bb][c]  = x[(size_t)(b0 + bb) * 128 + c];
  }
  __syncthreads();
  const int lane = tid & 63, wv = tid >> 6;
  for (int o = wv; o < 256; o += 4) {
    float acc[16];
#pragma unroll
    for (int bb = 0; bb < 16; ++bb) acc[bb] = 0.f;
    for (int it = 0; it < 256; ++it) {
      int k = it * 64 + lane;
      float wval = W[(size_t)o * 16384 + k];
      int f = k >> 7, p = k & 127;
#pragma unroll
      for (int bb = 0; bb < 16; ++bb)
        acc[bb] += wval * (x0_s[bb][f] * x_s[bb][p]);
    }
#pragma unroll
    for (int bb = 0; bb < 16; ++bb) {
      float v = acc[bb];
      for (int off = 32; off; off >>= 1) v += __shfl_down(v, off);
      if (lane == 0) out[(size_t)(b0 + bb) * 256 + o] = v + bias[o];
    }
  }
}

// ------------------------------- launcher ----------------------------------
extern "C" void kernel_launch(void* const* d_in, const int* in_sizes, int n_in,
                              void* d_out, int out_size, void* d_ws,
                              size_t ws_size, hipStream_t stream)
{
  const float* x0   = (const float*)d_in[0];
  const float* x    = (const float*)d_in[1];
  const float* W    = (const float*)d_in[2];
  const float* bias = (const float*)d_in[3];
  float* out = (float*)d_out;

  if (ws_size >= (size_t)WS_NEEDED) {
    _Float16* WT2  = (_Float16*)((char*)d_ws + WS_WT_OFF);
    _Float16* Xf   = (_Float16*)((char*)d_ws + WS_XF_OFF);
    _Float16* X0T2 = (_Float16*)((char*)d_ws + WS_X0_OFF);
    prep_kernel<<<2560, 256, 0, stream>>>(x0, x, W, WT2, Xf, X0T2);
    gemm_kernel<<<256, 512, 0, stream>>>(WT2, Xf, X0T2, bias, out);
  } else {
    naive_kernel<<<256, 256, 0, stream>>>(x0, x, W, bias, out);
  }
}